// Round 1
// baseline (1099.670 us; speedup 1.0000x reference)
//
#include <hip/hip_runtime.h>

#define H   128
#define H2  256
#define NG  256
#define NT  40
#define NF  9
#define TBM 32

// ---------------- h0 = node_emb[x] ----------------
__global__ void k_h0(const int* __restrict__ x, const float* __restrict__ emb,
                     float* __restrict__ h, int N) {
  int i = blockIdx.x * blockDim.x + threadIdx.x;   // over N*32 float4s
  if (i >= N * 32) return;
  int v = i >> 5, q = i & 31;
  ((float4*)h)[i] = ((const float4*)emb)[x[v] * 32 + q];
}

// ---------------- degree + edge_attr sums ----------------
__global__ void k_deg_s(const int* __restrict__ ei, const float* __restrict__ ea,
                        unsigned* __restrict__ deg, float* __restrict__ S, int E) {
  int e = blockIdx.x * blockDim.x + threadIdx.x;
  if (e >= E) return;
  int dst = ei[e];
  atomicAdd(&deg[dst], 1u);
  const float* a = ea + (size_t)e * NF;
  float* s = S + (size_t)dst * NF;
#pragma unroll
  for (int f = 0; f < NF; f++) atomicAdd(&s[f], a[f]);
}

// ---------------- exclusive scan of deg -> off, cur ----------------
__global__ void k_scan(const unsigned* __restrict__ deg, unsigned* __restrict__ off,
                       unsigned* __restrict__ cur, int N) {
  __shared__ unsigned sdata[1024];
  __shared__ unsigned s_run;
  int tid = threadIdx.x;
  if (tid == 0) s_run = 0u;
  __syncthreads();
  for (int base = 0; base < N; base += 4096) {
    unsigned v0 = 0, v1 = 0, v2 = 0, v3 = 0;
    int i0 = base + tid * 4;
    if (i0 + 0 < N) v0 = deg[i0 + 0];
    if (i0 + 1 < N) v1 = deg[i0 + 1];
    if (i0 + 2 < N) v2 = deg[i0 + 2];
    if (i0 + 3 < N) v3 = deg[i0 + 3];
    unsigned p0 = 0, p1 = v0, p2 = v0 + v1, p3 = v0 + v1 + v2;
    unsigned sum = p3 + v3;
    sdata[tid] = sum;
    __syncthreads();
    for (int d = 1; d < 1024; d <<= 1) {
      unsigned t = (tid >= d) ? sdata[tid - d] : 0u;
      __syncthreads();
      sdata[tid] += t;
      __syncthreads();
    }
    unsigned excl = sdata[tid] - sum + s_run;
    if (i0 + 0 < N) { off[i0 + 0] = excl + p0; cur[i0 + 0] = excl + p0; }
    if (i0 + 1 < N) { off[i0 + 1] = excl + p1; cur[i0 + 1] = excl + p1; }
    if (i0 + 2 < N) { off[i0 + 2] = excl + p2; cur[i0 + 2] = excl + p2; }
    if (i0 + 3 < N) { off[i0 + 3] = excl + p3; cur[i0 + 3] = excl + p3; }
    __syncthreads();
    if (tid == 1023) s_run += sdata[1023];
    __syncthreads();
  }
  if (tid == 0) off[N] = s_run;
}

// ---------------- scatter edge sources into CSR ----------------
__global__ void k_scatter(const int* __restrict__ ei, unsigned* __restrict__ cur,
                          int* __restrict__ csrc, int E) {
  int e = blockIdx.x * blockDim.x + threadIdx.x;
  if (e >= E) return;
  int dst = ei[e], src = ei[E + e];
  unsigned pos = atomicAdd(&cur[dst], 1u);
  csrc[pos] = src;
}

// ---------------- hsum[v] = h[v] + sum_{incoming} h[src] ----------------
__global__ __launch_bounds__(256) void k_gather(const float* __restrict__ h,
    const unsigned* __restrict__ off, const int* __restrict__ csrc,
    float* __restrict__ hs, int N) {
  int v = blockIdx.x * 4 + (threadIdx.x >> 6);
  int lane = threadIdx.x & 63;
  if (v >= N) return;
  unsigned o = off[v], e = off[v + 1];
  const float2* hp = (const float2*)h;
  float2 acc = hp[(size_t)v * 64 + lane];
  for (unsigned i = o; i < e; i++) {
    int s = csrc[i];
    float2 t = hp[(size_t)s * 64 + lane];
    acc.x += t.x; acc.y += t.y;
  }
  ((float2*)hs)[(size_t)v * 64 + lane] = acc;
}

// ---------------- per-layer folded constants ----------------
// M[f][c] = sum_k enc_w[f][k] * w1[H+k][c];  u[c] = sum_k enc_b[k]*w1[H+k][c]
// cc: [0]=bn scale, [1]=bn shift, [2]=u, [3]=K0 (= slt*M[sli]+u+b1)
__global__ void k_prep(const float* __restrict__ enc_w, const float* __restrict__ enc_b,
                       const float* __restrict__ w1, const float* __restrict__ b1,
                       const float* __restrict__ gamma, const float* __restrict__ beta,
                       const float* __restrict__ mean, const float* __restrict__ var,
                       const int* __restrict__ sli, const int* __restrict__ slt,
                       float* __restrict__ M, float* __restrict__ cc) {
  int c = threadIdx.x;  // 256 threads
  float m[NF];
  float u = 0.f;
#pragma unroll
  for (int f = 0; f < NF; f++) m[f] = 0.f;
  for (int k = 0; k < H; k++) {
    float wv = w1[(H + k) * H2 + c];
#pragma unroll
    for (int f = 0; f < NF; f++) m[f] += enc_w[f * H + k] * wv;
    u += enc_b[k] * wv;
  }
#pragma unroll
  for (int f = 0; f < NF; f++) M[f * H2 + c] = m[f];
  float sc = gamma[c] * rsqrtf(var[c] + 1e-5f);
  float sh = beta[c] - mean[c] * sc;
  float k0 = (float)(*slt) * M[(*sli) * H2 + c] + u + b1[c];
  cc[0 * H2 + c] = sc;
  cc[1 * H2 + c] = sh;
  cc[2 * H2 + c] = u;
  cc[3 * H2 + c] = k0;
}

// ---------------- fused GIN layer: z = BNReLU(hsum@w1_top + S@M + deg*u + K0); out = z@w2 + b2 ----------------
__global__ __launch_bounds__(256) void k_layer(
    const float* __restrict__ hs, const float* __restrict__ S,
    const unsigned* __restrict__ deg,
    const float* __restrict__ M, const float* __restrict__ cc,
    const float* __restrict__ w1, const float* __restrict__ w2,
    const float* __restrict__ b2,
    float* __restrict__ out, const int* __restrict__ batch,
    int N, int relu_out, int pool) {
  __shared__ float sh_hs[TBM][H];      // 16 KB
  __shared__ float sh_z[TBM][H2];      // 32 KB
  __shared__ float sh_M[NF][H2];       // 9 KB
  __shared__ float sh_S[TBM][NF];      // 1.1 KB
  __shared__ float sh_deg[TBM];
  int tid = threadIdx.x;
  int row0 = blockIdx.x * TBM;

  for (int i = tid; i < TBM * (H / 4); i += 256) {
    int r = i >> 5, q = i & 31;
    int v = row0 + r;
    float4 val = (v < N) ? ((const float4*)hs)[(size_t)v * (H / 4) + q]
                         : make_float4(0.f, 0.f, 0.f, 0.f);
    ((float4*)sh_hs[r])[q] = val;
  }
  for (int i = tid; i < NF * (H2 / 4); i += 256)
    ((float4*)sh_M)[i] = ((const float4*)M)[i];
  for (int i = tid; i < TBM * NF; i += 256) {
    int r = i / NF, f = i - r * NF;
    int v = row0 + r;
    sh_S[r][f] = (v < N) ? S[(size_t)v * NF + f] : 0.f;
  }
  if (tid < TBM) {
    int v = row0 + tid;
    sh_deg[tid] = (v < N) ? (float)deg[v] : 0.f;
  }
  __syncthreads();

  // ---- Phase A: z[32][256], micro-tile 4 rows x 8 cols per thread ----
  {
    int cg = tid & 31;   // cols cg*8 .. cg*8+7
    int rg = tid >> 5;   // rows rg*4 .. rg*4+3
    float acc[4][8];
#pragma unroll
    for (int r = 0; r < 4; r++)
#pragma unroll
      for (int c = 0; c < 8; c++) acc[r][c] = 0.f;

    const float* wbase = w1 + cg * 8;
    for (int k = 0; k < H; k += 4) {
      float av[4][4];
#pragma unroll
      for (int r = 0; r < 4; r++) {
        float4 t = *((const float4*)&sh_hs[rg * 4 + r][k]);
        av[r][0] = t.x; av[r][1] = t.y; av[r][2] = t.z; av[r][3] = t.w;
      }
      float bv[4][8];
#pragma unroll
      for (int kk = 0; kk < 4; kk++) {
        float4 t0 = ((const float4*)(wbase + (size_t)(k + kk) * H2))[0];
        float4 t1 = ((const float4*)(wbase + (size_t)(k + kk) * H2))[1];
        bv[kk][0] = t0.x; bv[kk][1] = t0.y; bv[kk][2] = t0.z; bv[kk][3] = t0.w;
        bv[kk][4] = t1.x; bv[kk][5] = t1.y; bv[kk][6] = t1.z; bv[kk][7] = t1.w;
      }
#pragma unroll
      for (int r = 0; r < 4; r++)
#pragma unroll
        for (int c = 0; c < 8; c++)
#pragma unroll
          for (int kk = 0; kk < 4; kk++)
            acc[r][c] += av[r][kk] * bv[kk][c];
    }

    // S@M
    float sv[4][NF];
#pragma unroll
    for (int r = 0; r < 4; r++)
#pragma unroll
      for (int f = 0; f < NF; f++) sv[r][f] = sh_S[rg * 4 + r][f];
#pragma unroll
    for (int f = 0; f < NF; f++) {
      float mv[8];
      float4 t0 = *((const float4*)&sh_M[f][cg * 8]);
      float4 t1 = *((const float4*)&sh_M[f][cg * 8 + 4]);
      mv[0] = t0.x; mv[1] = t0.y; mv[2] = t0.z; mv[3] = t0.w;
      mv[4] = t1.x; mv[5] = t1.y; mv[6] = t1.z; mv[7] = t1.w;
#pragma unroll
      for (int r = 0; r < 4; r++)
#pragma unroll
        for (int c = 0; c < 8; c++) acc[r][c] += sv[r][f] * mv[c];
    }

    // deg*u + K0, BN, ReLU -> sh_z
    float dg[4];
#pragma unroll
    for (int r = 0; r < 4; r++) dg[r] = sh_deg[rg * 4 + r];
    int cb = cg * 8;
    float scv[8], shv[8], uv[8], k0v[8];
    {
      float4 a0 = ((const float4*)(cc + 0 * H2 + cb))[0];
      float4 a1 = ((const float4*)(cc + 0 * H2 + cb))[1];
      scv[0]=a0.x; scv[1]=a0.y; scv[2]=a0.z; scv[3]=a0.w; scv[4]=a1.x; scv[5]=a1.y; scv[6]=a1.z; scv[7]=a1.w;
      float4 b0 = ((const float4*)(cc + 1 * H2 + cb))[0];
      float4 b1v = ((const float4*)(cc + 1 * H2 + cb))[1];
      shv[0]=b0.x; shv[1]=b0.y; shv[2]=b0.z; shv[3]=b0.w; shv[4]=b1v.x; shv[5]=b1v.y; shv[6]=b1v.z; shv[7]=b1v.w;
      float4 c0 = ((const float4*)(cc + 2 * H2 + cb))[0];
      float4 c1 = ((const float4*)(cc + 2 * H2 + cb))[1];
      uv[0]=c0.x; uv[1]=c0.y; uv[2]=c0.z; uv[3]=c0.w; uv[4]=c1.x; uv[5]=c1.y; uv[6]=c1.z; uv[7]=c1.w;
      float4 d0 = ((const float4*)(cc + 3 * H2 + cb))[0];
      float4 d1 = ((const float4*)(cc + 3 * H2 + cb))[1];
      k0v[0]=d0.x; k0v[1]=d0.y; k0v[2]=d0.z; k0v[3]=d0.w; k0v[4]=d1.x; k0v[5]=d1.y; k0v[6]=d1.z; k0v[7]=d1.w;
    }
#pragma unroll
    for (int r = 0; r < 4; r++) {
#pragma unroll
      for (int c = 0; c < 8; c++) {
        float z = acc[r][c] + dg[r] * uv[c] + k0v[c];
        z = z * scv[c] + shv[c];
        z = fmaxf(z, 0.f);
        sh_z[rg * 4 + r][cb + c] = z;
      }
    }
  }
  __syncthreads();

  // ---- Phase B: out[32][128] = sh_z @ w2 + b2 ----
  {
    int cg = tid & 31;   // cols cg*4 .. cg*4+3
    int rg = tid >> 5;   // rows rg*4 .. rg*4+3
    float acc[4][4];
#pragma unroll
    for (int r = 0; r < 4; r++)
#pragma unroll
      for (int c = 0; c < 4; c++) acc[r][c] = 0.f;

    const float* w2b = w2 + cg * 4;
    for (int k = 0; k < H2; k += 4) {
      float av[4][4];
#pragma unroll
      for (int r = 0; r < 4; r++) {
        float4 t = *((const float4*)&sh_z[rg * 4 + r][k]);
        av[r][0] = t.x; av[r][1] = t.y; av[r][2] = t.z; av[r][3] = t.w;
      }
      float bv[4][4];
#pragma unroll
      for (int kk = 0; kk < 4; kk++) {
        float4 t = ((const float4*)(w2b + (size_t)(k + kk) * H))[0];
        bv[kk][0] = t.x; bv[kk][1] = t.y; bv[kk][2] = t.z; bv[kk][3] = t.w;
      }
#pragma unroll
      for (int r = 0; r < 4; r++)
#pragma unroll
        for (int c = 0; c < 4; c++)
#pragma unroll
          for (int kk = 0; kk < 4; kk++)
            acc[r][c] += av[r][kk] * bv[kk][c];
    }

    float4 bb = ((const float4*)(b2 + cg * 4))[0];
    float bvv[4] = {bb.x, bb.y, bb.z, bb.w};
#pragma unroll
    for (int r = 0; r < 4; r++) {
      int v = row0 + rg * 4 + r;
      if (v >= N) continue;
      float vals[4];
#pragma unroll
      for (int c = 0; c < 4; c++) {
        float z = acc[r][c] + bvv[c];
        if (relu_out) z = fmaxf(z, 0.f);
        vals[c] = z;
      }
      if (pool) {
        int g = batch[v];
#pragma unroll
        for (int c = 0; c < 4; c++)
          atomicAdd(&out[(size_t)g * H + cg * 4 + c], vals[c]);
      } else {
        float4 st = make_float4(vals[0], vals[1], vals[2], vals[3]);
        ((float4*)(out + (size_t)v * H))[cg] = st;
      }
    }
  }
}

// ---------------- graph node counts ----------------
__global__ void k_cnt(const int* __restrict__ batch, float* __restrict__ cnt, int N) {
  int v = blockIdx.x * blockDim.x + threadIdx.x;
  if (v < N) atomicAdd(&cnt[batch[v]], 1.0f);
}

// ---------------- prediction head ----------------
__global__ void k_pred(const float* __restrict__ pooled, const float* __restrict__ cnt,
                       const float* __restrict__ pw, const float* __restrict__ pb,
                       float* __restrict__ outp) {
  int g = blockIdx.x;
  int t = threadIdx.x;
  if (t >= NT) return;
  float acc = 0.f;
  for (int k = 0; k < H; k++)
    acc += pooled[(size_t)g * H + k] * (pw[k * NT + t] + pw[(H + k) * NT + t]);
  float c = fmaxf(cnt[g], 1.0f);
  outp[(size_t)g * NT + t] = acc / c + pb[t];
}

extern "C" void kernel_launch(void* const* d_in, const int* in_sizes, int n_in,
                              void* d_out, int out_size, void* d_ws, size_t ws_size,
                              hipStream_t stream) {
  const int*   x     = (const int*)d_in[0];
  const int*   ei    = (const int*)d_in[1];
  const float* ea    = (const float*)d_in[2];
  const int*   batch = (const int*)d_in[3];
  const int*   sli   = (const int*)d_in[4];
  const int*   slt   = (const int*)d_in[5];
  const float* emb   = (const float*)d_in[6];
  const float* encw[2] = {(const float*)d_in[7],  (const float*)d_in[17]};
  const float* encb[2] = {(const float*)d_in[8],  (const float*)d_in[18]};
  const float* w1[2]   = {(const float*)d_in[9],  (const float*)d_in[19]};
  const float* b1[2]   = {(const float*)d_in[10], (const float*)d_in[20]};
  const float* gam[2]  = {(const float*)d_in[11], (const float*)d_in[21]};
  const float* bet[2]  = {(const float*)d_in[12], (const float*)d_in[22]};
  const float* mea[2]  = {(const float*)d_in[13], (const float*)d_in[23]};
  const float* var[2]  = {(const float*)d_in[14], (const float*)d_in[24]};
  const float* w2[2]   = {(const float*)d_in[15], (const float*)d_in[25]};
  const float* b2[2]   = {(const float*)d_in[16], (const float*)d_in[26]};
  const float* pw = (const float*)d_in[27];
  const float* pb = (const float*)d_in[28];

  int N = in_sizes[0];
  int E = in_sizes[1] / 2;

  char* p = (char*)d_ws;
  auto alloc = [&](size_t bytes) {
    char* r = p;
    p += (bytes + 255) / 256 * 256;
    return r;
  };
  unsigned* deg    = (unsigned*)alloc((size_t)N * 4);
  float*    S      = (float*)alloc((size_t)N * NF * 4);
  unsigned* off    = (unsigned*)alloc((size_t)(N + 1) * 4);
  unsigned* cur    = (unsigned*)alloc((size_t)N * 4);
  int*      csrc   = (int*)alloc((size_t)E * 4);
  float*    hA     = (float*)alloc((size_t)N * H * 4);
  float*    hS     = (float*)alloc((size_t)N * H * 4);
  float*    hB     = (float*)alloc((size_t)N * H * 4);
  float*    M      = (float*)alloc((size_t)NF * H2 * 4);
  float*    cc     = (float*)alloc((size_t)4 * H2 * 4);
  float*    pooled = (float*)alloc((size_t)NG * H * 4);
  float*    cnt    = (float*)alloc((size_t)NG * 4);

  hipMemsetAsync(deg, 0, (size_t)N * 4, stream);
  hipMemsetAsync(S, 0, (size_t)N * NF * 4, stream);
  hipMemsetAsync(pooled, 0, (size_t)NG * H * 4, stream);
  hipMemsetAsync(cnt, 0, (size_t)NG * 4, stream);

  k_h0<<<(N * 32 + 255) / 256, 256, 0, stream>>>(x, emb, hA, N);
  k_deg_s<<<(E + 255) / 256, 256, 0, stream>>>(ei, ea, deg, S, E);
  k_scan<<<1, 1024, 0, stream>>>(deg, off, cur, N);
  k_scatter<<<(E + 255) / 256, 256, 0, stream>>>(ei, cur, csrc, E);

  // layer 0
  k_prep<<<1, 256, 0, stream>>>(encw[0], encb[0], w1[0], b1[0], gam[0], bet[0],
                                mea[0], var[0], sli, slt, M, cc);
  k_gather<<<(N + 3) / 4, 256, 0, stream>>>(hA, off, csrc, hS, N);
  k_layer<<<(N + TBM - 1) / TBM, 256, 0, stream>>>(hS, S, deg, M, cc, w1[0], w2[0],
                                                   b2[0], hB, batch, N, 1, 0);
  // layer 1 (output pooled directly)
  k_prep<<<1, 256, 0, stream>>>(encw[1], encb[1], w1[1], b1[1], gam[1], bet[1],
                                mea[1], var[1], sli, slt, M, cc);
  k_gather<<<(N + 3) / 4, 256, 0, stream>>>(hB, off, csrc, hS, N);
  k_layer<<<(N + TBM - 1) / TBM, 256, 0, stream>>>(hS, S, deg, M, cc, w1[1], w2[1],
                                                   b2[1], pooled, batch, N, 0, 1);

  k_cnt<<<(N + 255) / 256, 256, 0, stream>>>(batch, cnt, N);
  k_pred<<<NG, 64, 0, stream>>>(pooled, cnt, pw, pb, (float*)d_out);
}

// Round 2
// 821.897 us; speedup vs baseline: 1.3380x; 1.3380x over previous
//
#include <hip/hip_runtime.h>

#define H   128
#define H2  256
#define NG  256
#define NT  40
#define NF  9
#define TBM 32

// ---------------- h0 = node_emb[x] ----------------
__global__ void k_h0(const int* __restrict__ x, const float* __restrict__ emb,
                     float* __restrict__ h, int N) {
  int i = blockIdx.x * blockDim.x + threadIdx.x;   // over N*32 float4s
  if (i >= N * 32) return;
  int v = i >> 5, q = i & 31;
  ((float4*)h)[i] = ((const float4*)emb)[x[v] * 32 + q];
}

// ---------------- degree only (1 atomic per edge) ----------------
__global__ void k_deg(const int* __restrict__ ei, unsigned* __restrict__ deg, int E) {
  int e = blockIdx.x * blockDim.x + threadIdx.x;
  if (e >= E) return;
  atomicAdd(&deg[ei[e]], 1u);
}

// ---------------- exclusive scan of deg -> off, cur (wave-shfl scan) ----------------
__global__ __launch_bounds__(1024) void k_scan(const unsigned* __restrict__ deg,
                                               unsigned* __restrict__ off,
                                               unsigned* __restrict__ cur, int N) {
  __shared__ unsigned wsum[16];
  __shared__ unsigned wpre[16];
  __shared__ unsigned s_run;
  int tid = threadIdx.x;
  int lane = tid & 63, wv = tid >> 6;
  if (tid == 0) s_run = 0u;
  __syncthreads();
  for (int base = 0; base < N; base += 4096) {
    int i0 = base + tid * 4;
    unsigned v0 = 0, v1 = 0, v2 = 0, v3 = 0;
    if (i0 + 0 < N) v0 = deg[i0 + 0];
    if (i0 + 1 < N) v1 = deg[i0 + 1];
    if (i0 + 2 < N) v2 = deg[i0 + 2];
    if (i0 + 3 < N) v3 = deg[i0 + 3];
    unsigned tsum = v0 + v1 + v2 + v3;
    // inclusive wave scan of tsum
    unsigned sc = tsum;
#pragma unroll
    for (int d = 1; d < 64; d <<= 1) {
      unsigned t = __shfl_up(sc, d);
      if (lane >= d) sc += t;
    }
    if (lane == 63) wsum[wv] = sc;
    __syncthreads();
    if (wv == 0 && lane < 16) {
      unsigned xv = wsum[lane];
#pragma unroll
      for (int d = 1; d < 16; d <<= 1) {
        unsigned t = __shfl_up(xv, d);
        if (lane >= d) xv += t;
      }
      wpre[lane] = xv;  // inclusive over wave sums
    }
    __syncthreads();
    unsigned excl = s_run + (wv ? wpre[wv - 1] : 0u) + (sc - tsum);
    unsigned p1 = excl + v0, p2 = p1 + v1, p3 = p2 + v2;
    if (i0 + 0 < N) { off[i0 + 0] = excl; cur[i0 + 0] = excl; }
    if (i0 + 1 < N) { off[i0 + 1] = p1;   cur[i0 + 1] = p1; }
    if (i0 + 2 < N) { off[i0 + 2] = p2;   cur[i0 + 2] = p2; }
    if (i0 + 3 < N) { off[i0 + 3] = p3;   cur[i0 + 3] = p3; }
    __syncthreads();
    if (tid == 0) s_run += wpre[15];
  }
  if (tid == 0) off[N] = s_run;
}

// ---------------- scatter edge src + edge id into CSR ----------------
__global__ void k_scatter(const int* __restrict__ ei, unsigned* __restrict__ cur,
                          int* __restrict__ csrc, int* __restrict__ ceid, int E) {
  int e = blockIdx.x * blockDim.x + threadIdx.x;
  if (e >= E) return;
  int dst = ei[e], src = ei[E + e];
  unsigned pos = atomicAdd(&cur[dst], 1u);
  csrc[pos] = src;
  ceid[pos] = e;
}

// ---------------- S[v] = sum of ea rows of incoming edges (CSR, no atomics) ----------------
__global__ __launch_bounds__(256) void k_S(const float* __restrict__ ea,
    const unsigned* __restrict__ off, const int* __restrict__ ceid,
    float* __restrict__ S, int N) {
  int lane = threadIdx.x & 63;
  int wv = threadIdx.x >> 6;
  int sub = lane & 7;                       // 8 lanes per node
  int v = blockIdx.x * 32 + wv * 8 + (lane >> 3);
  if (v >= N) return;
  unsigned o = off[v], e = off[v + 1];
  float acc[NF];
#pragma unroll
  for (int f = 0; f < NF; f++) acc[f] = 0.f;
  for (unsigned i = o + sub; i < e; i += 8) {
    const float* a = ea + (size_t)ceid[i] * NF;
#pragma unroll
    for (int f = 0; f < NF; f++) acc[f] += a[f];
  }
#pragma unroll
  for (int d = 1; d < 8; d <<= 1)
#pragma unroll
    for (int f = 0; f < NF; f++) acc[f] += __shfl_xor(acc[f], d);
  if (sub == 0) {
#pragma unroll
    for (int f = 0; f < NF; f++) S[(size_t)v * NF + f] = acc[f];
  }
}

// ---------------- hsum[v] = h[v] + sum_{incoming} h[src] ----------------
__global__ __launch_bounds__(256) void k_gather(const float* __restrict__ h,
    const unsigned* __restrict__ off, const int* __restrict__ csrc,
    float* __restrict__ hs, int N) {
  int v = blockIdx.x * 4 + (threadIdx.x >> 6);
  int lane = threadIdx.x & 63;
  if (v >= N) return;
  unsigned o = off[v], e = off[v + 1];
  const float2* hp = (const float2*)h;
  float2 acc = hp[(size_t)v * 64 + lane];
  for (unsigned i = o; i < e; i++) {
    int s = csrc[i];
    float2 t = hp[(size_t)s * 64 + lane];
    acc.x += t.x; acc.y += t.y;
  }
  ((float2*)hs)[(size_t)v * 64 + lane] = acc;
}

// ---------------- per-layer folded constants ----------------
// M[f][c] = sum_k enc_w[f][k] * w1[H+k][c];  u[c] = sum_k enc_b[k]*w1[H+k][c]
// cc: [0]=bn scale, [1]=bn shift, [2]=u, [3]=K0 (= slt*M[sli]+u+b1)
__global__ void k_prep(const float* __restrict__ enc_w, const float* __restrict__ enc_b,
                       const float* __restrict__ w1, const float* __restrict__ b1,
                       const float* __restrict__ gamma, const float* __restrict__ beta,
                       const float* __restrict__ mean, const float* __restrict__ var,
                       const int* __restrict__ sli, const int* __restrict__ slt,
                       float* __restrict__ M, float* __restrict__ cc) {
  int c = threadIdx.x;  // 256 threads
  float m[NF];
  float u = 0.f;
#pragma unroll
  for (int f = 0; f < NF; f++) m[f] = 0.f;
  for (int k = 0; k < H; k++) {
    float wv = w1[(H + k) * H2 + c];
#pragma unroll
    for (int f = 0; f < NF; f++) m[f] += enc_w[f * H + k] * wv;
    u += enc_b[k] * wv;
  }
#pragma unroll
  for (int f = 0; f < NF; f++) M[f * H2 + c] = m[f];
  float sc = gamma[c] * rsqrtf(var[c] + 1e-5f);
  float sh = beta[c] - mean[c] * sc;
  float k0 = (float)(*slt) * m[*sli] + u + b1[c];
  cc[0 * H2 + c] = sc;
  cc[1 * H2 + c] = sh;
  cc[2 * H2 + c] = u;
  cc[3 * H2 + c] = k0;
}

// ---------------- fused GIN layer: z = BNReLU(hsum@w1_top + S@M + deg*u + K0); out = z@w2 + b2 ----------------
__global__ __launch_bounds__(256) void k_layer(
    const float* __restrict__ hs, const float* __restrict__ S,
    const unsigned* __restrict__ deg,
    const float* __restrict__ M, const float* __restrict__ cc,
    const float* __restrict__ w1, const float* __restrict__ w2,
    const float* __restrict__ b2,
    float* __restrict__ out, const int* __restrict__ batch,
    int N, int relu_out, int pool) {
  __shared__ float sh_hs[TBM][H];      // 16 KB
  __shared__ float sh_z[TBM][H2];      // 32 KB
  __shared__ float sh_M[NF][H2];       // 9 KB
  __shared__ float sh_S[TBM][NF];      // 1.1 KB
  __shared__ float sh_deg[TBM];
  int tid = threadIdx.x;
  int row0 = blockIdx.x * TBM;

  for (int i = tid; i < TBM * (H / 4); i += 256) {
    int r = i >> 5, q = i & 31;
    int v = row0 + r;
    float4 val = (v < N) ? ((const float4*)hs)[(size_t)v * (H / 4) + q]
                         : make_float4(0.f, 0.f, 0.f, 0.f);
    ((float4*)sh_hs[r])[q] = val;
  }
  for (int i = tid; i < NF * (H2 / 4); i += 256)
    ((float4*)sh_M)[i] = ((const float4*)M)[i];
  for (int i = tid; i < TBM * NF; i += 256) {
    int r = i / NF, f = i - r * NF;
    int v = row0 + r;
    sh_S[r][f] = (v < N) ? S[(size_t)v * NF + f] : 0.f;
  }
  if (tid < TBM) {
    int v = row0 + tid;
    sh_deg[tid] = (v < N) ? (float)deg[v] : 0.f;
  }
  __syncthreads();

  // ---- Phase A: z[32][256], micro-tile 4 rows x 8 cols per thread ----
  {
    int cg = tid & 31;   // cols cg*8 .. cg*8+7
    int rg = tid >> 5;   // rows rg*4 .. rg*4+3
    float acc[4][8];
#pragma unroll
    for (int r = 0; r < 4; r++)
#pragma unroll
      for (int c = 0; c < 8; c++) acc[r][c] = 0.f;

    const float* wbase = w1 + cg * 8;
    for (int k = 0; k < H; k += 4) {
      float av[4][4];
#pragma unroll
      for (int r = 0; r < 4; r++) {
        float4 t = *((const float4*)&sh_hs[rg * 4 + r][k]);
        av[r][0] = t.x; av[r][1] = t.y; av[r][2] = t.z; av[r][3] = t.w;
      }
      float bv[4][8];
#pragma unroll
      for (int kk = 0; kk < 4; kk++) {
        float4 t0 = ((const float4*)(wbase + (size_t)(k + kk) * H2))[0];
        float4 t1 = ((const float4*)(wbase + (size_t)(k + kk) * H2))[1];
        bv[kk][0] = t0.x; bv[kk][1] = t0.y; bv[kk][2] = t0.z; bv[kk][3] = t0.w;
        bv[kk][4] = t1.x; bv[kk][5] = t1.y; bv[kk][6] = t1.z; bv[kk][7] = t1.w;
      }
#pragma unroll
      for (int r = 0; r < 4; r++)
#pragma unroll
        for (int c = 0; c < 8; c++)
#pragma unroll
          for (int kk = 0; kk < 4; kk++)
            acc[r][c] += av[r][kk] * bv[kk][c];
    }

    // S@M
    float sv[4][NF];
#pragma unroll
    for (int r = 0; r < 4; r++)
#pragma unroll
      for (int f = 0; f < NF; f++) sv[r][f] = sh_S[rg * 4 + r][f];
#pragma unroll
    for (int f = 0; f < NF; f++) {
      float mv[8];
      float4 t0 = *((const float4*)&sh_M[f][cg * 8]);
      float4 t1 = *((const float4*)&sh_M[f][cg * 8 + 4]);
      mv[0] = t0.x; mv[1] = t0.y; mv[2] = t0.z; mv[3] = t0.w;
      mv[4] = t1.x; mv[5] = t1.y; mv[6] = t1.z; mv[7] = t1.w;
#pragma unroll
      for (int r = 0; r < 4; r++)
#pragma unroll
        for (int c = 0; c < 8; c++) acc[r][c] += sv[r][f] * mv[c];
    }

    // deg*u + K0, BN, ReLU -> sh_z
    float dg[4];
#pragma unroll
    for (int r = 0; r < 4; r++) dg[r] = sh_deg[rg * 4 + r];
    int cb = cg * 8;
    float scv[8], shv[8], uv[8], k0v[8];
    {
      float4 a0 = ((const float4*)(cc + 0 * H2 + cb))[0];
      float4 a1 = ((const float4*)(cc + 0 * H2 + cb))[1];
      scv[0]=a0.x; scv[1]=a0.y; scv[2]=a0.z; scv[3]=a0.w; scv[4]=a1.x; scv[5]=a1.y; scv[6]=a1.z; scv[7]=a1.w;
      float4 b0 = ((const float4*)(cc + 1 * H2 + cb))[0];
      float4 b1v = ((const float4*)(cc + 1 * H2 + cb))[1];
      shv[0]=b0.x; shv[1]=b0.y; shv[2]=b0.z; shv[3]=b0.w; shv[4]=b1v.x; shv[5]=b1v.y; shv[6]=b1v.z; shv[7]=b1v.w;
      float4 c0 = ((const float4*)(cc + 2 * H2 + cb))[0];
      float4 c1 = ((const float4*)(cc + 2 * H2 + cb))[1];
      uv[0]=c0.x; uv[1]=c0.y; uv[2]=c0.z; uv[3]=c0.w; uv[4]=c1.x; uv[5]=c1.y; uv[6]=c1.z; uv[7]=c1.w;
      float4 d0 = ((const float4*)(cc + 3 * H2 + cb))[0];
      float4 d1 = ((const float4*)(cc + 3 * H2 + cb))[1];
      k0v[0]=d0.x; k0v[1]=d0.y; k0v[2]=d0.z; k0v[3]=d0.w; k0v[4]=d1.x; k0v[5]=d1.y; k0v[6]=d1.z; k0v[7]=d1.w;
    }
#pragma unroll
    for (int r = 0; r < 4; r++) {
#pragma unroll
      for (int c = 0; c < 8; c++) {
        float z = acc[r][c] + dg[r] * uv[c] + k0v[c];
        z = z * scv[c] + shv[c];
        z = fmaxf(z, 0.f);
        sh_z[rg * 4 + r][cb + c] = z;
      }
    }
  }
  __syncthreads();

  // ---- Phase B: out[32][128] = sh_z @ w2 + b2 ----
  {
    int cg = tid & 31;   // cols cg*4 .. cg*4+3
    int rg = tid >> 5;   // rows rg*4 .. rg*4+3
    float acc[4][4];
#pragma unroll
    for (int r = 0; r < 4; r++)
#pragma unroll
      for (int c = 0; c < 4; c++) acc[r][c] = 0.f;

    const float* w2b = w2 + cg * 4;
    for (int k = 0; k < H2; k += 4) {
      float av[4][4];
#pragma unroll
      for (int r = 0; r < 4; r++) {
        float4 t = *((const float4*)&sh_z[rg * 4 + r][k]);
        av[r][0] = t.x; av[r][1] = t.y; av[r][2] = t.z; av[r][3] = t.w;
      }
      float bv[4][4];
#pragma unroll
      for (int kk = 0; kk < 4; kk++) {
        float4 t = ((const float4*)(w2b + (size_t)(k + kk) * H))[0];
        bv[kk][0] = t.x; bv[kk][1] = t.y; bv[kk][2] = t.z; bv[kk][3] = t.w;
      }
#pragma unroll
      for (int r = 0; r < 4; r++)
#pragma unroll
        for (int c = 0; c < 4; c++)
#pragma unroll
          for (int kk = 0; kk < 4; kk++)
            acc[r][c] += av[r][kk] * bv[kk][c];
    }

    float4 bb = ((const float4*)(b2 + cg * 4))[0];
    float bvv[4] = {bb.x, bb.y, bb.z, bb.w};
#pragma unroll
    for (int r = 0; r < 4; r++) {
      int v = row0 + rg * 4 + r;
      if (v >= N) continue;
      float vals[4];
#pragma unroll
      for (int c = 0; c < 4; c++) {
        float z = acc[r][c] + bvv[c];
        if (relu_out) z = fmaxf(z, 0.f);
        vals[c] = z;
      }
      if (pool) {
        int g = batch[v];
#pragma unroll
        for (int c = 0; c < 4; c++)
          atomicAdd(&out[(size_t)g * H + cg * 4 + c], vals[c]);
      } else {
        float4 st = make_float4(vals[0], vals[1], vals[2], vals[3]);
        ((float4*)(out + (size_t)v * H))[cg] = st;
      }
    }
  }
}

// ---------------- graph node counts ----------------
__global__ void k_cnt(const int* __restrict__ batch, float* __restrict__ cnt, int N) {
  int v = blockIdx.x * blockDim.x + threadIdx.x;
  if (v < N) atomicAdd(&cnt[batch[v]], 1.0f);
}

// ---------------- prediction head ----------------
__global__ void k_pred(const float* __restrict__ pooled, const float* __restrict__ cnt,
                       const float* __restrict__ pw, const float* __restrict__ pb,
                       float* __restrict__ outp) {
  int g = blockIdx.x;
  int t = threadIdx.x;
  if (t >= NT) return;
  float acc = 0.f;
  for (int k = 0; k < H; k++)
    acc += pooled[(size_t)g * H + k] * (pw[k * NT + t] + pw[(H + k) * NT + t]);
  float c = fmaxf(cnt[g], 1.0f);
  outp[(size_t)g * NT + t] = acc / c + pb[t];
}

extern "C" void kernel_launch(void* const* d_in, const int* in_sizes, int n_in,
                              void* d_out, int out_size, void* d_ws, size_t ws_size,
                              hipStream_t stream) {
  const int*   x     = (const int*)d_in[0];
  const int*   ei    = (const int*)d_in[1];
  const float* ea    = (const float*)d_in[2];
  const int*   batch = (const int*)d_in[3];
  const int*   sli   = (const int*)d_in[4];
  const int*   slt   = (const int*)d_in[5];
  const float* emb   = (const float*)d_in[6];
  const float* encw[2] = {(const float*)d_in[7],  (const float*)d_in[17]};
  const float* encb[2] = {(const float*)d_in[8],  (const float*)d_in[18]};
  const float* w1[2]   = {(const float*)d_in[9],  (const float*)d_in[19]};
  const float* b1[2]   = {(const float*)d_in[10], (const float*)d_in[20]};
  const float* gam[2]  = {(const float*)d_in[11], (const float*)d_in[21]};
  const float* bet[2]  = {(const float*)d_in[12], (const float*)d_in[22]};
  const float* mea[2]  = {(const float*)d_in[13], (const float*)d_in[23]};
  const float* var[2]  = {(const float*)d_in[14], (const float*)d_in[24]};
  const float* w2[2]   = {(const float*)d_in[15], (const float*)d_in[25]};
  const float* b2[2]   = {(const float*)d_in[16], (const float*)d_in[26]};
  const float* pw = (const float*)d_in[27];
  const float* pb = (const float*)d_in[28];

  int N = in_sizes[0];
  int E = in_sizes[1] / 2;

  char* p = (char*)d_ws;
  auto alloc = [&](size_t bytes) {
    char* r = p;
    p += (bytes + 255) / 256 * 256;
    return r;
  };
  unsigned* deg    = (unsigned*)alloc((size_t)N * 4);
  float*    S      = (float*)alloc((size_t)N * NF * 4);
  unsigned* off    = (unsigned*)alloc((size_t)(N + 1) * 4);
  unsigned* cur    = (unsigned*)alloc((size_t)N * 4);
  int*      csrc   = (int*)alloc((size_t)E * 4);
  int*      ceid   = (int*)alloc((size_t)E * 4);
  float*    hA     = (float*)alloc((size_t)N * H * 4);
  float*    hS     = (float*)alloc((size_t)N * H * 4);
  float*    hB     = (float*)alloc((size_t)N * H * 4);
  float*    M      = (float*)alloc((size_t)NF * H2 * 4);
  float*    cc     = (float*)alloc((size_t)4 * H2 * 4);
  float*    pooled = (float*)alloc((size_t)NG * H * 4);
  float*    cnt    = (float*)alloc((size_t)NG * 4);

  hipMemsetAsync(deg, 0, (size_t)N * 4, stream);
  hipMemsetAsync(pooled, 0, (size_t)NG * H * 4, stream);
  hipMemsetAsync(cnt, 0, (size_t)NG * 4, stream);

  k_h0<<<(N * 32 + 255) / 256, 256, 0, stream>>>(x, emb, hA, N);
  k_deg<<<(E + 255) / 256, 256, 0, stream>>>(ei, deg, E);
  k_scan<<<1, 1024, 0, stream>>>(deg, off, cur, N);
  k_scatter<<<(E + 255) / 256, 256, 0, stream>>>(ei, cur, csrc, ceid, E);
  k_S<<<(N + 31) / 32, 256, 0, stream>>>(ea, off, ceid, S, N);

  // layer 0
  k_prep<<<1, 256, 0, stream>>>(encw[0], encb[0], w1[0], b1[0], gam[0], bet[0],
                                mea[0], var[0], sli, slt, M, cc);
  k_gather<<<(N + 3) / 4, 256, 0, stream>>>(hA, off, csrc, hS, N);
  k_layer<<<(N + TBM - 1) / TBM, 256, 0, stream>>>(hS, S, deg, M, cc, w1[0], w2[0],
                                                   b2[0], hB, batch, N, 1, 0);
  // layer 1 (output pooled directly)
  k_prep<<<1, 256, 0, stream>>>(encw[1], encb[1], w1[1], b1[1], gam[1], bet[1],
                                mea[1], var[1], sli, slt, M, cc);
  k_gather<<<(N + 3) / 4, 256, 0, stream>>>(hB, off, csrc, hS, N);
  k_layer<<<(N + TBM - 1) / TBM, 256, 0, stream>>>(hS, S, deg, M, cc, w1[1], w2[1],
                                                   b2[1], pooled, batch, N, 0, 1);

  k_cnt<<<(N + 255) / 256, 256, 0, stream>>>(batch, cnt, N);
  k_pred<<<NG, 64, 0, stream>>>(pooled, cnt, pw, pb, (float*)d_out);
}